// Round 11
// baseline (229.364 us; speedup 1.0000x reference)
//
#include <hip/hip_runtime.h>
#include <hip/hip_cooperative_groups.h>
#include <math.h>

namespace cg = cooperative_groups;

#define LN_EPS 1e-5f
#define EPS_ATTN 1e-8f
#define SCALE 0.125f  // D^-0.5, D=64
#define CHUNKS 16     // stream work items per batch (256 rows each)

struct KArgs {
  const float *inputs, *noise, *mu, *lsig;
  const float *wq, *bq, *wk, *bk, *wv, *bv;
  const float *w_ih, *b_ih, *w_hh, *b_hh;
  const float *w1, *b1, *w2, *b2;
  const float *g_in, *beta_in, *g_sl, *beta_sl, *g_ff, *beta_ff;
  float *S_buf, *qk, *qb, *acc, *asum;
  float *M, *cvec, *uvec, *s0v;
  float *out;
};

// ---------------------------------------------------------------------------
__device__ __forceinline__ float wsum64(float v) {
#pragma unroll
  for (int m = 1; m <= 32; m <<= 1) v += __shfl_xor(v, m, 64);
  return v;
}

// 16-lane allreduce sum on the VALU pipe via DPP (no LDS-pipe traffic).
__device__ __forceinline__ float red16(float v) {
  v += __int_as_float(__builtin_amdgcn_update_dpp(0, __float_as_int(v), 0xB1, 0xF, 0xF, true));
  v += __int_as_float(__builtin_amdgcn_update_dpp(0, __float_as_int(v), 0x4E, 0xF, 0xF, true));
  v += __int_as_float(__builtin_amdgcn_update_dpp(0, __float_as_int(v), 0x124, 0xF, 0xF, true));
  v += __int_as_float(__builtin_amdgcn_update_dpp(0, __float_as_int(v), 0x128, 0xF, 0xF, true));
  return v;
}

// Agent-scope relaxed atomics: per-access coherent (bypass possibly-stale
// L1/L2), no cache-maintenance storms. Proven bit-exact in round 2.
__device__ __forceinline__ float ald(const float* p) {
  return __hip_atomic_load(p, __ATOMIC_RELAXED, __HIP_MEMORY_SCOPE_AGENT);
}
__device__ __forceinline__ void ast(float* p, float v) {
  __hip_atomic_store(p, v, __ATOMIC_RELAXED, __HIP_MEMORY_SCOPE_AGENT);
}

// ---------------------------------------------------------------------------
// Init work item (577 wave-sized items): slots + qk/qb direct, M/cvec/uvec/s0.
__device__ void init_work(int bi, int lane, const KArgs& a) {
  if (bi < 512) {
    float sl = a.mu[lane] + __expf(a.lsig[lane]) * a.noise[bi * 64 + lane];
    ast(a.S_buf + bi * 64 + lane, sl);
    ast(a.acc + bi * 64 + lane, 0.0f);
    if (lane == 0) ast(a.asum + bi, 0.0f);

    float s  = wsum64(sl);
    float s2 = wsum64(sl * sl);
    float mean = s * (1.0f / 64.0f);
    float var  = s2 * (1.0f / 64.0f) - mean * mean;
    float rstd = rsqrtf(var + LN_EPS);
    float ln = (sl - mean) * rstd * a.g_sl[lane] + a.beta_sl[lane];

    float q = a.bq[lane];
#pragma unroll
    for (int t = 0; t < 64; ++t) q += __shfl(ln, t, 64) * a.wq[t * 64 + lane];
    float qkl = 0.0f;
#pragma unroll
    for (int d = 0; d < 64; ++d) qkl += __shfl(q, d, 64) * a.wk[lane * 64 + d];
    ast(a.qk + bi * 64 + lane, qkl * SCALE);
    float qbl = wsum64(q * a.bk[lane]);
    if (lane == 0) ast(a.qb + bi, qbl * SCALE);
  } else if (bi < 576) {
    int t = bi - 512;
    float wqv = a.wq[t * 64 + lane];
    float m = 0.0f;
#pragma unroll
    for (int d = 0; d < 64; ++d) m += __shfl(wqv, d, 64) * a.wk[lane * 64 + d];
    a.M[t * 64 + lane] = m * SCALE;              // write-once, fenced by grid.sync
    float uv = wsum64(wqv * a.bk[lane]);
    if (lane == 0) a.uvec[t] = uv * SCALE;
  } else {
    float bqv = a.bq[lane];
    float cc = 0.0f;
#pragma unroll
    for (int j = 0; j < 64; ++j) cc += __shfl(bqv, j, 64) * a.wk[lane * 64 + j];
    a.cvec[lane] = cc * SCALE;
    float ss = wsum64(a.bq[lane] * a.bk[lane]);
    if (lane == 0) a.s0v[0] = ss * SCALE;
  }
}

// ---------------------------------------------------------------------------
// Stream work item: one (batch, chunk) = 256 rows, 256 threads (R7 body,
// 8 iterations). qk/qb staged to LDS via agent loads.
__device__ void stream_work(int b, int chunk, int tid, const KArgs& a,
                            float* lds_qk, float* lds_qb,
                            float (*lds_acc)[512], float (*lds_as)[8]) {
  const int lane = tid & 63;
  const int wave = tid >> 6;
  const int p = lane & 15;

  for (int i = tid; i < 512; i += 256) lds_qk[i] = ald(a.qk + b * 512 + i);
  if (tid < 8) lds_qb[tid] = ald(a.qb + b * 8 + tid);

  float4 g4  = ((const float4*)a.g_in)[p];
  float4 be4 = ((const float4*)a.beta_in)[p];

  float4 accl[8];
  float asl[8];
#pragma unroll
  for (int i = 0; i < 8; ++i) { accl[i] = make_float4(0.f, 0.f, 0.f, 0.f); asl[i] = 0.f; }

  __syncthreads();  // lds_qk/lds_qb ready (also orders vs prior item's LDS use)

  const float4* in4 = (const float4*)(a.inputs + (size_t)b * 4096 * 64);
  const float4* qk4 = (const float4*)lds_qk;
  const int rb0 = chunk * 256 + wave * 8;

  for (int it = 0; it < 8; ++it) {
    float4 xa = in4[(rb0 + it * 32) * 16 + lane];
    float4 xb = in4[(rb0 + it * 32 + 4) * 16 + lane];

    float sA  = red16(xa.x + xa.y + xa.z + xa.w);
    float s2A = red16(xa.x * xa.x + xa.y * xa.y + xa.z * xa.z + xa.w * xa.w);
    float meanA = sA * 0.015625f;
    float varA  = s2A * 0.015625f - meanA * meanA;
    float rstdA = rsqrtf(varA + LN_EPS);
    float4 xlnA;
    xlnA.x = (xa.x - meanA) * rstdA * g4.x + be4.x;
    xlnA.y = (xa.y - meanA) * rstdA * g4.y + be4.y;
    xlnA.z = (xa.z - meanA) * rstdA * g4.z + be4.z;
    xlnA.w = (xa.w - meanA) * rstdA * g4.w + be4.w;

    float sB  = red16(xb.x + xb.y + xb.z + xb.w);
    float s2B = red16(xb.x * xb.x + xb.y * xb.y + xb.z * xb.z + xb.w * xb.w);
    float meanB = sB * 0.015625f;
    float varB  = s2B * 0.015625f - meanB * meanB;
    float rstdB = rsqrtf(varB + LN_EPS);
    float4 xlnB;
    xlnB.x = (xb.x - meanB) * rstdB * g4.x + be4.x;
    xlnB.y = (xb.y - meanB) * rstdB * g4.y + be4.y;
    xlnB.z = (xb.z - meanB) * rstdB * g4.z + be4.z;
    xlnB.w = (xb.w - meanB) * rstdB * g4.w + be4.w;

    float pvA[8], pvB[8];
    float psA = 0.0f, psB = 0.0f;
#pragma unroll
    for (int i = 0; i < 8; ++i) {
      float4 qv = qk4[i * 16 + p];
      float qbi = lds_qb[i];
      float da = xlnA.x * qv.x + xlnA.y * qv.y + xlnA.z * qv.z + xlnA.w * qv.w;
      float db = xlnB.x * qv.x + xlnB.y * qv.y + xlnB.z * qv.z + xlnB.w * qv.w;
      da = red16(da) + qbi;
      db = red16(db) + qbi;
      float ea = __expf(da);   // no max-subtraction (|dots| << 88)
      float eb = __expf(db);
      pvA[i] = ea; psA += ea;
      pvB[i] = eb; psB += eb;
    }
    float invA = __builtin_amdgcn_rcpf(psA);
    float invB = __builtin_amdgcn_rcpf(psB);
#pragma unroll
    for (int i = 0; i < 8; ++i) {
      float ppa = pvA[i] * invA + EPS_ATTN;
      float ppb = pvB[i] * invB + EPS_ATTN;
      asl[i] += ppa + ppb;
      accl[i].x += ppa * xlnA.x; accl[i].x += ppb * xlnB.x;
      accl[i].y += ppa * xlnA.y; accl[i].y += ppb * xlnB.y;
      accl[i].z += ppa * xlnA.z; accl[i].z += ppb * xlnB.z;
      accl[i].w += ppa * xlnA.w; accl[i].w += ppb * xlnB.w;
    }
  }

#pragma unroll
  for (int i = 0; i < 8; ++i) {
#pragma unroll
    for (int m = 16; m <= 32; m <<= 1) {
      accl[i].x += __shfl_xor(accl[i].x, m, 64);
      accl[i].y += __shfl_xor(accl[i].y, m, 64);
      accl[i].z += __shfl_xor(accl[i].z, m, 64);
      accl[i].w += __shfl_xor(accl[i].w, m, 64);
      asl[i]    += __shfl_xor(asl[i], m, 64);
    }
  }

  if (lane < 16) {
    float4* dst = (float4*)lds_acc[wave];
#pragma unroll
    for (int i = 0; i < 8; ++i) dst[i * 16 + p] = accl[i];
  }
  if (lane == 0) {
#pragma unroll
    for (int i = 0; i < 8; ++i) lds_as[wave][i] = asl[i];
  }
  __syncthreads();

  for (int f = tid; f < 512; f += 256) {
    float ssum = lds_acc[0][f] + lds_acc[1][f] + lds_acc[2][f] + lds_acc[3][f];
    atomicAdd(&a.acc[b * 512 + f], ssum);
  }
  if (tid < 8) {
    float ssum = lds_as[0][tid] + lds_as[1][tid] + lds_as[2][tid] + lds_as[3][tid];
    atomicAdd(&a.asum[b * 8 + tid], ssum);
  }
}

// ---------------------------------------------------------------------------
// Slot-update work item: 4 waves per slot (R4/R7-proven body). acc/asum read
// with agent loads; cross-phase outputs written with agent stores.
__device__ void update_work(int bi, int do_next, float* dstS, int tid,
                            const KArgs& a, float (*red)[4][64]) {
  const int lane = tid & 63;
  const int w    = tid >> 6;
  const int e0   = w * 16;

  __syncthreads();  // protect red[] against the previous item's tail reads

  float asv = ald(a.asum + bi);
  float v   = ald(a.acc + bi * 64 + lane) / asv;
  float sp  = ald(a.S_buf + bi * 64 + lane);

  // ---- seg1: updates = v @ wv + bv ----
  float up = 0.0f;
#pragma unroll
  for (int e = 0; e < 16; ++e) {
    float vv = __shfl(v, e0 + e, 64);
    up += vv * a.wv[(e0 + e) * 64 + lane];
  }
  red[0][w][lane] = up;
  __syncthreads();
  float upd = a.bv[lane] + red[0][0][lane] + red[0][1][lane]
                         + red[0][2][lane] + red[0][3][lane];

  // ---- seg2: GRU gates ----
  float gxr = 0, gxz = 0, gxn = 0, ghr = 0, ghz = 0, ghn = 0;
#pragma unroll
  for (int e = 0; e < 16; ++e) {
    int ee = e0 + e;
    float uu = __shfl(upd, ee, 64);
    float hh = __shfl(sp, ee, 64);
    const float* wi = a.w_ih + ee * 192;
    const float* wh = a.w_hh + ee * 192;
    gxr += uu * wi[lane]; gxz += uu * wi[64 + lane]; gxn += uu * wi[128 + lane];
    ghr += hh * wh[lane]; ghz += hh * wh[64 + lane]; ghn += hh * wh[128 + lane];
  }
  __syncthreads();
  red[0][w][lane] = gxr; red[1][w][lane] = gxz; red[2][w][lane] = gxn;
  red[3][w][lane] = ghr; red[4][w][lane] = ghz; red[5][w][lane] = ghn;
  __syncthreads();
  gxr = a.b_ih[lane]       + red[0][0][lane] + red[0][1][lane] + red[0][2][lane] + red[0][3][lane];
  gxz = a.b_ih[64 + lane]  + red[1][0][lane] + red[1][1][lane] + red[1][2][lane] + red[1][3][lane];
  gxn = a.b_ih[128 + lane] + red[2][0][lane] + red[2][1][lane] + red[2][2][lane] + red[2][3][lane];
  ghr = a.b_hh[lane]       + red[3][0][lane] + red[3][1][lane] + red[3][2][lane] + red[3][3][lane];
  ghz = a.b_hh[64 + lane]  + red[4][0][lane] + red[4][1][lane] + red[4][2][lane] + red[4][3][lane];
  ghn = a.b_hh[128 + lane] + red[5][0][lane] + red[5][1][lane] + red[5][2][lane] + red[5][3][lane];

  float r  = 1.0f / (1.0f + __expf(-(gxr + ghr)));
  float z  = 1.0f / (1.0f + __expf(-(gxz + ghz)));
  float nw = tanhf(gxn + r * ghn);
  float sn = (1.0f - z) * nw + z * sp;   // identical in all 4 waves

  float s  = wsum64(sn);
  float s2 = wsum64(sn * sn);
  float mean = s * (1.0f / 64.0f);
  float var  = s2 * (1.0f / 64.0f) - mean * mean;
  float rstd = rsqrtf(var + LN_EPS);
  float ff = (sn - mean) * rstd * a.g_ff[lane] + a.beta_ff[lane];

  // ---- seg3: hidden = relu(ff @ w1 + b1) ----
  float h1 = 0.0f, h2 = 0.0f;
#pragma unroll
  for (int e = 0; e < 16; ++e) {
    int ee = e0 + e;
    float f = __shfl(ff, ee, 64);
    h1 += f * a.w1[ee * 128 + lane];
    h2 += f * a.w1[ee * 128 + 64 + lane];
  }
  __syncthreads();
  red[0][w][lane] = h1; red[1][w][lane] = h2;
  __syncthreads();
  h1 = fmaxf(a.b1[lane]      + red[0][0][lane] + red[0][1][lane] + red[0][2][lane] + red[0][3][lane], 0.0f);
  h2 = fmaxf(a.b1[64 + lane] + red[1][0][lane] + red[1][1][lane] + red[1][2][lane] + red[1][3][lane], 0.0f);

  // ---- seg4: out = sn + hidden @ w2 + b2 ----
  float po = 0.0f;
#pragma unroll
  for (int t = 0; t < 16; ++t) {
    int tt = e0 + t;
    po += __shfl(h1, tt, 64) * a.w2[tt * 64 + lane];
    po += __shfl(h2, tt, 64) * a.w2[(64 + tt) * 64 + lane];
  }
  __syncthreads();
  red[0][w][lane] = po;
  __syncthreads();
  float o = sn + a.b2[lane] + red[0][0][lane] + red[0][1][lane]
                            + red[0][2][lane] + red[0][3][lane];
  if (w == 0) ast(dstS + bi * 64 + lane, o);

  if (do_next && w == 0) {
    ast(a.acc + bi * 64 + lane, 0.0f);
    if (lane == 0) ast(a.asum + bi, 0.0f);
  }

  if (do_next) {
    float so  = wsum64(o);
    float so2 = wsum64(o * o);
    float mo  = so * (1.0f / 64.0f);
    float vo  = so2 * (1.0f / 64.0f) - mo * mo;
    float ro  = rsqrtf(vo + LN_EPS);
    float ln  = (o - mo) * ro * a.g_sl[lane] + a.beta_sl[lane];

    float pq = 0.0f;
#pragma unroll
    for (int t = 0; t < 16; ++t) {
      int tt = e0 + t;
      pq += __shfl(ln, tt, 64) * a.M[tt * 64 + lane];
    }
    __syncthreads();
    red[1][w][lane] = pq;
    __syncthreads();
    if (w == 0) {
      ast(a.qk + bi * 64 + lane,
          a.cvec[lane] + red[1][0][lane] + red[1][1][lane]
                       + red[1][2][lane] + red[1][3][lane]);
      float pb = wsum64(ln * a.uvec[lane]);
      if (lane == 0) ast(a.qb + bi, a.s0v[0] + pb);
    }
  }
}

// ---------------------------------------------------------------------------
// Single cooperative kernel: init -> 3x(stream, update) with grid.sync()
// between phases. Grid-stride loops make any grid size correct.
__global__ __launch_bounds__(256) void k_coop(KArgs a) {
  __shared__ float lds_qk[512];
  __shared__ float lds_qb[8];
  __shared__ float lds_acc[4][512];   // update phase reuses this as red[6][4][64]
  __shared__ float lds_as[4][8];
  cg::grid_group grid = cg::this_grid();
  const int tid = threadIdx.x;
  const int nb = gridDim.x;

  for (int w = blockIdx.x * 4 + (tid >> 6); w < 577; w += nb * 4)
    init_work(w, tid & 63, a);
  grid.sync();

  for (int t = 0; t < 3; ++t) {
    for (int w = blockIdx.x; w < 64 * CHUNKS; w += nb)
      stream_work(w >> 4, w & (CHUNKS - 1), tid, a, lds_qk, lds_qb, lds_acc, lds_as);
    grid.sync();
    float* dst = (t == 2) ? a.out : a.S_buf;
    for (int u = blockIdx.x; u < 512; u += nb)
      update_work(u, (t < 2) ? 1 : 0, dst, tid, a, (float(*)[4][64])lds_acc);
    if (t < 2) grid.sync();
  }
}

// ---------------------------------------------------------------------------
// Fallback split kernels (R7 structure; taken if cooperative launch rejected).
__global__ __launch_bounds__(64) void k_init_sep(KArgs a) {
  init_work(blockIdx.x, threadIdx.x, a);
}
__global__ __launch_bounds__(256) void k_main_sep(KArgs a) {
  __shared__ float lds_qk[512];
  __shared__ float lds_qb[8];
  __shared__ float lds_acc[4][512];
  __shared__ float lds_as[4][8];
  stream_work(blockIdx.y, blockIdx.x, threadIdx.x, a, lds_qk, lds_qb, lds_acc, lds_as);
}
__global__ __launch_bounds__(256) void k_update_sep(KArgs a, int t) {
  __shared__ float red[6][4][64];
  update_work(blockIdx.x, (t < 2) ? 1 : 0, (t == 2) ? a.out : a.S_buf,
              threadIdx.x, a, red);
}

// ---------------------------------------------------------------------------
extern "C" void kernel_launch(void* const* d_in, const int* in_sizes, int n_in,
                              void* d_out, int out_size, void* d_ws, size_t ws_size,
                              hipStream_t stream) {
  KArgs a;
  a.inputs  = (const float*)d_in[0];
  a.noise   = (const float*)d_in[1];
  a.mu      = (const float*)d_in[2];
  a.lsig    = (const float*)d_in[3];
  a.wq      = (const float*)d_in[4];
  a.bq      = (const float*)d_in[5];
  a.wk      = (const float*)d_in[6];
  a.bk      = (const float*)d_in[7];
  a.wv      = (const float*)d_in[8];
  a.bv      = (const float*)d_in[9];
  a.w_ih    = (const float*)d_in[10];
  a.b_ih    = (const float*)d_in[11];
  a.w_hh    = (const float*)d_in[12];
  a.b_hh    = (const float*)d_in[13];
  a.w1      = (const float*)d_in[14];
  a.b1      = (const float*)d_in[15];
  a.w2      = (const float*)d_in[16];
  a.b2      = (const float*)d_in[17];
  a.g_in    = (const float*)d_in[18];
  a.beta_in = (const float*)d_in[19];
  a.g_sl    = (const float*)d_in[20];
  a.beta_sl = (const float*)d_in[21];
  a.g_ff    = (const float*)d_in[22];
  a.beta_ff = (const float*)d_in[23];

  float* ws = (float*)d_ws;
  a.S_buf = ws;                // [512*64]
  a.qk    = ws + 32768;        // [512*64]
  a.qb    = a.qk + 32768;      // [512]
  a.acc   = a.qb + 512;        // [512*64]
  a.asum  = a.acc + 32768;     // [512]
  a.M     = a.asum + 512;      // [64*64]
  a.cvec  = a.M + 4096;        // [64]
  a.uvec  = a.cvec + 64;       // [64]
  a.s0v   = a.uvec + 64;       // [1]
  a.out   = (float*)d_out;

  // ---- try the single-dispatch cooperative path ----
  bool coop_ok = false;
  int nb = 0;
  if (hipOccupancyMaxActiveBlocksPerMultiprocessor(
          &nb, (const void*)k_coop, 256, 0) == hipSuccess && nb >= 1) {
    int ncu = 256;  // MI355X
    hipDeviceProp_t prop;
    int dev = 0;
    if (hipGetDevice(&dev) == hipSuccess &&
        hipGetDeviceProperties(&prop, dev) == hipSuccess &&
        prop.multiProcessorCount > 0)
      ncu = prop.multiProcessorCount;
    int grid = nb * ncu;
    if (grid > 64 * CHUNKS) grid = 64 * CHUNKS;
    void* args[] = { (void*)&a };
    if (hipLaunchCooperativeKernel((const void*)k_coop, dim3(grid), dim3(256),
                                   args, 0, stream) == hipSuccess)
      coop_ok = true;
  }

  // ---- fallback: proven 7-dispatch split structure ----
  if (!coop_ok) {
    k_init_sep<<<577, 64, 0, stream>>>(a);
    for (int t = 0; t < 3; ++t) {
      k_main_sep<<<dim3(CHUNKS, 64), 256, 0, stream>>>(a);
      k_update_sep<<<512, 256, 0, stream>>>(a, t);
    }
  }
}